// Round 1
// baseline (210.239 us; speedup 1.0000x reference)
//
#include <hip/hip_runtime.h>
#include <math.h>

// Problem constants (N=4, R=16384, K=96)
#define NRAYS   65536        // N*R
#define KSAMP   96
#define KM1     95
#define RPB     4            // rays per block: one 64-lane wave per ray, 256 threads
// Output tuple flat layout: rgb [NRAYS*3] | depth [NRAYS] | weights [NRAYS*95]
#define RGB_OFF   0
#define DEPTH_OFF (NRAYS * 3)                // 196608
#define W_OFF     (NRAYS * 3 + NRAYS)        // 262144

// ---------------------------------------------------------------------------
// ws[0] = uint bits of global min of first midpoints (init 0xFFFFFFFF)
// ws[1] = uint bits of global max of last midpoints  (init 0)
// (uint ordering == float ordering for positive floats; depths in [0.5, 3.5])
// ---------------------------------------------------------------------------
__global__ void init_mm(unsigned int* mm) {
    mm[0] = 0xFFFFFFFFu;
    mm[1] = 0u;
}

__global__ __launch_bounds__(256) void minmax_kernel(const float* __restrict__ depths,
                                                     unsigned int* __restrict__ mm) {
    int ray = blockIdx.x * blockDim.x + threadIdx.x;   // grid exactly covers NRAYS
    const float* d = depths + (size_t)ray * KSAMP;
    // depths sorted along K: per-ray min midpoint is the first, max is the last
    float2 dfirst = *(const float2*)(d);               // d[0], d[1]
    float2 dlast  = *(const float2*)(d + KSAMP - 2);   // d[94], d[95]
    float m0 = 0.5f * (dfirst.x + dfirst.y);
    float ml = 0.5f * (dlast.x + dlast.y);
    #pragma unroll
    for (int off = 32; off; off >>= 1) {
        m0 = fminf(m0, __shfl_xor(m0, off));
        ml = fmaxf(ml, __shfl_xor(ml, off));
    }
    if ((threadIdx.x & 63) == 0) {                     // one atomic per wave
        atomicMin(mm + 0, __float_as_uint(m0));
        atomicMax(mm + 1, __float_as_uint(ml));
    }
}

// ---------------------------------------------------------------------------
// Main integrator: one wave per ray. Lane l owns intervals i=2l and i=2l+1.
// trans_i = prod_{j<i} (1-alpha_j+1e-10)  via wave prefix-product of per-lane
// chunk products (Hillis-Steele, identity 1.0 on out-of-range lanes).
// ---------------------------------------------------------------------------
__global__ __launch_bounds__(256) void integrate_kernel(
    const float* __restrict__ rgbs,     // [NRAYS, K, 3]
    const float* __restrict__ sigmas,   // [NRAYS, K]
    const float* __restrict__ depths,   // [NRAYS, K]
    float* __restrict__ out,
    const unsigned int* __restrict__ mm)
{
    __shared__ float sh_d[RPB * KSAMP];        // 384 floats
    __shared__ float sh_s[RPB * KSAMP];        // 384 floats
    __shared__ float sh_rgb[RPB * KSAMP * 3];  // 1152 floats

    const int tid  = threadIdx.x;
    const int ray0 = blockIdx.x * RPB;

    // Block-cooperative, fully coalesced float4 staging (bases are 16B aligned:
    // ray0*KSAMP*4 = ray0*384 bytes; ray0*KSAMP*3*4 = ray0*1152 bytes).
    {
        const float4* gd = (const float4*)(depths + (size_t)ray0 * KSAMP);      // 96 f4
        const float4* gs = (const float4*)(sigmas + (size_t)ray0 * KSAMP);      // 96 f4
        const float4* gr = (const float4*)(rgbs   + (size_t)ray0 * KSAMP * 3);  // 288 f4
        float4* sd4 = (float4*)sh_d;
        float4* ss4 = (float4*)sh_s;
        float4* sr4 = (float4*)sh_rgb;
        if (tid < 96) { sd4[tid] = gd[tid]; ss4[tid] = gs[tid]; }
        sr4[tid] = gr[tid];
        if (tid < 32) sr4[256 + tid] = gr[256 + tid];
    }
    __syncthreads();

    const int wave = tid >> 6;
    const int lane = tid & 63;
    const int ray  = ray0 + wave;
    const float* d  = sh_d   + wave * KSAMP;
    const float* s  = sh_s   + wave * KSAMP;
    const float* rg = sh_rgb + wave * KSAMP * 3;

    const int i0 = 2 * lane;
    const bool v0 = (i0     < KM1);
    const bool v1 = (i0 + 1 < KM1);

    float a0 = 0.f, a1 = 0.f, om0 = 1.f, om1 = 1.f;
    float dm0 = 0.f, dm1 = 0.f;
    float rm00 = 0.f, rm01 = 0.f, rm02 = 0.f;
    float rm10 = 0.f, rm11 = 0.f, rm12 = 0.f;

    if (v0) {
        float dA = d[i0], dB = d[i0 + 1];
        float delta = dB - dA;
        float x = 0.5f * (s[i0] + s[i0 + 1]) - 1.0f;            // mipnerf clamp arg
        float sp = (x > 0.f) ? (x + log1pf(expf(-x))) : log1pf(expf(x));  // softplus
        float e = expf(-delta * sp);
        a0 = 1.f - e;
        om0 = e + 1e-10f;
        dm0 = 0.5f * (dA + dB);
        rm00 = 0.5f * (rg[3*i0 + 0] + rg[3*i0 + 3]);
        rm01 = 0.5f * (rg[3*i0 + 1] + rg[3*i0 + 4]);
        rm02 = 0.5f * (rg[3*i0 + 2] + rg[3*i0 + 5]);
    }
    if (v1) {
        int i1 = i0 + 1;
        float dA = d[i1], dB = d[i1 + 1];
        float delta = dB - dA;
        float x = 0.5f * (s[i1] + s[i1 + 1]) - 1.0f;
        float sp = (x > 0.f) ? (x + log1pf(expf(-x))) : log1pf(expf(x));
        float e = expf(-delta * sp);
        a1 = 1.f - e;
        om1 = e + 1e-10f;
        dm1 = 0.5f * (dA + dB);
        rm10 = 0.5f * (rg[3*i1 + 0] + rg[3*i1 + 3]);
        rm11 = 0.5f * (rg[3*i1 + 1] + rg[3*i1 + 4]);
        rm12 = 0.5f * (rg[3*i1 + 2] + rg[3*i1 + 5]);
    }

    // Wave-wide exclusive prefix product of per-lane chunk products.
    float p = om0 * om1;            // identity 1.0 where invalid
    float incl = p;
    #pragma unroll
    for (int off = 1; off < 64; off <<= 1) {
        float u = __shfl_up(incl, off);
        if (lane >= off) incl *= u;
    }
    float excl = __shfl_up(incl, 1);
    if (lane == 0) excl = 1.f;

    float t0 = excl;                // trans for interval 2l
    float t1 = excl * om0;          // trans for interval 2l+1
    float w0 = v0 ? a0 * t0 : 0.f;
    float w1 = v1 ? a1 * t1 : 0.f;

    // weights output (third tuple element), [ray][i]
    float* wout = out + W_OFF + (size_t)ray * KM1;
    if (v0) wout[i0]     = w0;
    if (v1) wout[i0 + 1] = w1;

    // Composite reductions across the wave.
    float wsum = w0 + w1;
    float rsum = w0 * rm00 + w1 * rm10;
    float gsum = w0 * rm01 + w1 * rm11;
    float bsum = w0 * rm02 + w1 * rm12;
    float dsum = w0 * dm0  + w1 * dm1;
    #pragma unroll
    for (int off = 32; off; off >>= 1) {
        wsum += __shfl_xor(wsum, off);
        rsum += __shfl_xor(rsum, off);
        gsum += __shfl_xor(gsum, off);
        bsum += __shfl_xor(bsum, off);
        dsum += __shfl_xor(dsum, off);
    }

    if (lane == 0) {
        out[RGB_OFF + (size_t)ray * 3 + 0] = 2.f * rsum - 1.f;
        out[RGB_OFF + (size_t)ray * 3 + 1] = 2.f * gsum - 1.f;
        out[RGB_OFF + (size_t)ray * 3 + 2] = 2.f * bsum - 1.f;

        float dv = dsum / wsum;                 // normalize_depth
        if (isnan(dv)) dv = INFINITY;           // nan_to_num(nan=inf)
        float gmin = __uint_as_float(mm[0]);    // clip_depth to global midpoint range
        float gmax = __uint_as_float(mm[1]);
        dv = fminf(fmaxf(dv, gmin), gmax);
        out[DEPTH_OFF + ray] = dv;
    }
}

extern "C" void kernel_launch(void* const* d_in, const int* in_sizes, int n_in,
                              void* d_out, int out_size, void* d_ws, size_t ws_size,
                              hipStream_t stream) {
    const float* rgbs   = (const float*)d_in[0];
    const float* sigmas = (const float*)d_in[1];
    const float* depths = (const float*)d_in[2];
    float* out = (float*)d_out;
    unsigned int* mm = (unsigned int*)d_ws;

    init_mm<<<1, 1, 0, stream>>>(mm);
    minmax_kernel<<<NRAYS / 256, 256, 0, stream>>>(depths, mm);
    integrate_kernel<<<NRAYS / RPB, 256, 0, stream>>>(rgbs, sigmas, depths, out, mm);
}

// Round 2
// 159.387 us; speedup vs baseline: 1.3190x; 1.3190x over previous
//
#include <hip/hip_runtime.h>
#include <math.h>

// Problem constants (N=4, R=16384, K=96)
#define NRAYS   65536        // N*R
#define KSAMP   96
#define KM1     95
#define RPB     4            // rays per block: one 64-lane wave per ray, 256 threads
// Output tuple flat layout: rgb [NRAYS*3] | depth [NRAYS] | weights [NRAYS*95]
#define RGB_OFF   0
#define DEPTH_OFF (NRAYS * 3)                // 196608
#define W_OFF     (NRAYS * 3 + NRAYS)        // 262144

// 1 - alpha (core) = exp(-delta * softplus(x)) computed with HW transcendentals:
//   exp(-d*ln(1+e^x)) = 2^(-d*log2(1+2^(x*log2e)))
// 3 x v_exp/v_log_f32 instead of ~60 VALU instrs of libm expf/log1pf.
__device__ __forceinline__ float one_minus_alpha(float x, float delta) {
    const float L2E = 1.44269504088896340736f;
    float xl = x * L2E;
    // softplus(x)/ln2 = log2(1 + 2^xl); for large x it's just xl (guards exp overflow)
    float l2 = (x > 20.0f) ? xl
                           : __builtin_amdgcn_logf(1.0f + __builtin_amdgcn_exp2f(xl));
    return __builtin_amdgcn_exp2f(-delta * l2);
}

// ---------------------------------------------------------------------------
// One wave per ray. Lane l owns intervals i=2l and i=2l+1.
// trans_i = prod_{j<i} (1-alpha_j+1e-10)  via wave prefix-product.
// Depth clip uses RAY-LOCAL midpoint bounds: composite_depth is a convex
// combination of this ray's midpoints, so it lies inside
// [mid_first, mid_last] subset [global_min, global_max] -- the reference's
// global clip is an identity here (weights_sum>0 always: softplus>0, delta>0).
// ---------------------------------------------------------------------------
__global__ __launch_bounds__(256) void integrate_kernel(
    const float* __restrict__ rgbs,     // [NRAYS, K, 3]
    const float* __restrict__ sigmas,   // [NRAYS, K]
    const float* __restrict__ depths,   // [NRAYS, K]
    float* __restrict__ out)
{
    __shared__ float sh_d[RPB * KSAMP];        // 384 floats
    __shared__ float sh_s[RPB * KSAMP];        // 384 floats
    __shared__ float sh_rgb[RPB * KSAMP * 3];  // 1152 floats

    const int tid  = threadIdx.x;
    const int ray0 = blockIdx.x * RPB;

    // Block-cooperative, fully coalesced float4 staging.
    {
        const float4* gd = (const float4*)(depths + (size_t)ray0 * KSAMP);      // 96 f4
        const float4* gs = (const float4*)(sigmas + (size_t)ray0 * KSAMP);      // 96 f4
        const float4* gr = (const float4*)(rgbs   + (size_t)ray0 * KSAMP * 3);  // 288 f4
        float4* sd4 = (float4*)sh_d;
        float4* ss4 = (float4*)sh_s;
        float4* sr4 = (float4*)sh_rgb;
        if (tid < 96) { sd4[tid] = gd[tid]; ss4[tid] = gs[tid]; }
        sr4[tid] = gr[tid];
        if (tid < 32) sr4[256 + tid] = gr[256 + tid];
    }
    __syncthreads();

    const int wave = tid >> 6;
    const int lane = tid & 63;
    const int ray  = ray0 + wave;
    const float* d  = sh_d   + wave * KSAMP;
    const float* s  = sh_s   + wave * KSAMP;
    const float* rg = sh_rgb + wave * KSAMP * 3;

    const int i0 = 2 * lane;
    const bool v0 = (i0     < KM1);
    const bool v1 = (i0 + 1 < KM1);

    float a0 = 0.f, a1 = 0.f, om0 = 1.f, om1 = 1.f;
    float dm0 = 0.f, dm1 = 0.f;
    float rm00 = 0.f, rm01 = 0.f, rm02 = 0.f;
    float rm10 = 0.f, rm11 = 0.f, rm12 = 0.f;

    if (v0) {
        float dA = d[i0], dB = d[i0 + 1];
        float delta = dB - dA;
        float x = 0.5f * (s[i0] + s[i0 + 1]) - 1.0f;   // mipnerf clamp arg
        float e = one_minus_alpha(x, delta);
        a0 = 1.f - e;
        om0 = e + 1e-10f;
        dm0 = 0.5f * (dA + dB);
        rm00 = 0.5f * (rg[3*i0 + 0] + rg[3*i0 + 3]);
        rm01 = 0.5f * (rg[3*i0 + 1] + rg[3*i0 + 4]);
        rm02 = 0.5f * (rg[3*i0 + 2] + rg[3*i0 + 5]);
    }
    if (v1) {
        int i1 = i0 + 1;
        float dA = d[i1], dB = d[i1 + 1];
        float delta = dB - dA;
        float x = 0.5f * (s[i1] + s[i1 + 1]) - 1.0f;
        float e = one_minus_alpha(x, delta);
        a1 = 1.f - e;
        om1 = e + 1e-10f;
        dm1 = 0.5f * (dA + dB);
        rm10 = 0.5f * (rg[3*i1 + 0] + rg[3*i1 + 3]);
        rm11 = 0.5f * (rg[3*i1 + 1] + rg[3*i1 + 4]);
        rm12 = 0.5f * (rg[3*i1 + 2] + rg[3*i1 + 5]);
    }

    // Wave-wide exclusive prefix product of per-lane chunk products.
    float incl = om0 * om1;         // identity 1.0 where invalid
    #pragma unroll
    for (int off = 1; off < 64; off <<= 1) {
        float u = __shfl_up(incl, off);
        if (lane >= off) incl *= u;
    }
    float excl = __shfl_up(incl, 1);
    if (lane == 0) excl = 1.f;

    float w0 = v0 ? a0 * excl : 0.f;
    float w1 = v1 ? a1 * (excl * om0) : 0.f;

    // weights output (third tuple element), [ray][i]
    float* wout = out + W_OFF + (size_t)ray * KM1;
    if (v0) wout[i0]     = w0;
    if (v1) wout[i0 + 1] = w1;

    // Composite reductions across the wave.
    float wsum = w0 + w1;
    float rsum = w0 * rm00 + w1 * rm10;
    float gsum = w0 * rm01 + w1 * rm11;
    float bsum = w0 * rm02 + w1 * rm12;
    float dsum = w0 * dm0  + w1 * dm1;
    #pragma unroll
    for (int off = 32; off; off >>= 1) {
        wsum += __shfl_xor(wsum, off);
        rsum += __shfl_xor(rsum, off);
        gsum += __shfl_xor(gsum, off);
        bsum += __shfl_xor(bsum, off);
        dsum += __shfl_xor(dsum, off);
    }

    if (lane == 0) {
        out[RGB_OFF + (size_t)ray * 3 + 0] = 2.f * rsum - 1.f;
        out[RGB_OFF + (size_t)ray * 3 + 1] = 2.f * gsum - 1.f;
        out[RGB_OFF + (size_t)ray * 3 + 2] = 2.f * bsum - 1.f;

        float dv = dsum / wsum;                      // normalize_depth
        // ray-local midpoint bounds (depths sorted along K)
        float lo = 0.5f * (d[0]  + d[1]);
        float hi = 0.5f * (d[94] + d[95]);
        // fminf first: a NaN dv maps to hi (matches ref nan->inf->clip->max)
        dv = fmaxf(fminf(dv, hi), lo);
        out[DEPTH_OFF + ray] = dv;
    }
}

extern "C" void kernel_launch(void* const* d_in, const int* in_sizes, int n_in,
                              void* d_out, int out_size, void* d_ws, size_t ws_size,
                              hipStream_t stream) {
    const float* rgbs   = (const float*)d_in[0];
    const float* sigmas = (const float*)d_in[1];
    const float* depths = (const float*)d_in[2];
    float* out = (float*)d_out;

    integrate_kernel<<<NRAYS / RPB, 256, 0, stream>>>(rgbs, sigmas, depths, out);
}